// Round 1
// baseline (431.035 us; speedup 1.0000x reference)
//
#include <hip/hip_runtime.h>
#include <math.h>

#define BATCH 256
#define SEQ 100
#define DMODEL 256
#define DI 512
#define DID 512
#define NST 16
#define DTRANK 16
#define DCONV 4
#define NLAYERS 3

__device__ __forceinline__ float silu_f(float x) {
    return x / (1.0f + expf(-x));
}
__device__ __forceinline__ float softplus_f(float x) {
    return fmaxf(x, 0.0f) + log1pf(expf(-fabsf(x)));
}

// W2[i][j] = sum_c W_embed[i][c] * m_in_w[c][j];  b2[j] = sum_c b_embed[c] * m_in_w[c][j]
__global__ void k_prep(const float* __restrict__ W_embed, const float* __restrict__ b_embed,
                       const float* __restrict__ m_in_w, float* __restrict__ W2,
                       float* __restrict__ b2) {
    int j = blockIdx.x * blockDim.x + threadIdx.x;  // 0..1023
    float acc[8] = {0, 0, 0, 0, 0, 0, 0, 0};
    float accb = 0.f;
    for (int c = 0; c < DMODEL; ++c) {
        float w = m_in_w[c * 1024 + j];
        accb += b_embed[c] * w;
#pragma unroll
        for (int i = 0; i < 8; ++i) acc[i] += W_embed[i * DMODEL + c] * w;
    }
#pragma unroll
    for (int i = 0; i < 8; ++i) W2[i * 1024 + j] = acc[i];
    b2[j] = accb;
}

// xc[b,t,d] = silu( sum_k xs(b, t-3+k, d) * conv_w[d,k] + conv_b[d] )
// xs computed inline: xs(b,t',d) = sum_i x[b,t',i]*W2[i,d] + b2[d]   (0 if t'<0)
// At t==SEQ-1 also produce silu(z[b,d]) with z from W2 columns 512..1023.
__global__ void k_conv(const float* __restrict__ x, const float* __restrict__ W2,
                       const float* __restrict__ b2, const float* __restrict__ conv_w,
                       const float* __restrict__ conv_b, float* __restrict__ xc,
                       float* __restrict__ silu_z) {
    int bt = blockIdx.x >> 1;
    int d = ((blockIdx.x & 1) << 8) + threadIdx.x;  // 0..511
    int b = bt / SEQ, t = bt % SEQ;
    float w2c[8];
#pragma unroll
    for (int i = 0; i < 8; ++i) w2c[i] = W2[i * 1024 + d];
    float bias = b2[d];
    float xs[DCONV];
#pragma unroll
    for (int k = 0; k < DCONV; ++k) {
        int tp = t - (DCONV - 1) + k;
        float v = 0.f;
        if (tp >= 0) {
            const float* xr = x + (b * SEQ + tp) * 8;
            v = bias;
#pragma unroll
            for (int i = 0; i < 8; ++i) v += xr[i] * w2c[i];
        }
        xs[k] = v;
    }
    float acc = conv_b[d];
#pragma unroll
    for (int k = 0; k < DCONV; ++k) acc += xs[k] * conv_w[d * DCONV + k];
    xc[bt * DI + d] = silu_f(acc);
    if (t == SEQ - 1) {
        float z = b2[512 + d];
        const float* xr = x + (b * SEQ + t) * 8;
#pragma unroll
        for (int i = 0; i < 8; ++i) z += xr[i] * W2[i * 1024 + 512 + d];
        silu_z[b * DI + d] = silu_f(z);
    }
}

// proj[bt, j] = sum_c xc[bt, c] * xproj_w[c, j]   (j in 0..47)
__global__ void k_proj(const float* __restrict__ xc, const float* __restrict__ xproj_w,
                       float* __restrict__ proj) {
    int j = threadIdx.x % 48;
    int bt = blockIdx.x * 4 + threadIdx.x / 48;
    const float* row = xc + bt * DI;
    float acc = 0.f;
    for (int c = 0; c < DI; ++c) acc += row[c] * xproj_w[c * 48 + j];
    proj[bt * 48 + j] = acc;
}

// Sequential SSM scan over t; one thread per (b,d). Only final y (t=SEQ-1) kept.
__global__ void k_scan(const float* __restrict__ xc, const float* __restrict__ proj,
                       const float* __restrict__ A_log, const float* __restrict__ dtw,
                       const float* __restrict__ dtb, const float* __restrict__ Dvec,
                       const float* __restrict__ silu_z, float* __restrict__ y) {
    int b = blockIdx.x >> 1;
    int d = ((blockIdx.x & 1) << 8) + threadIdx.x;
    float An[NST], wr[DTRANK];
#pragma unroll
    for (int n = 0; n < NST; ++n) An[n] = -expf(A_log[d * NST + n]);
#pragma unroll
    for (int r = 0; r < DTRANK; ++r) wr[r] = dtw[r * DI + d];
    float bdt = dtb[d];
    float h[NST];
#pragma unroll
    for (int n = 0; n < NST; ++n) h[n] = 0.f;
    float xv = 0.f;
    const float* pb = proj + (size_t)(b * SEQ) * 48;
    const float* xb = xc + (size_t)(b * SEQ) * DI;
    for (int t = 0; t < SEQ; ++t) {
        const float* pr = pb + t * 48;
        float acc = bdt;
#pragma unroll
        for (int r = 0; r < DTRANK; ++r) acc += pr[r] * wr[r];
        float dtv = softplus_f(acc);
        xv = xb[t * DI + d];
        float s = dtv * xv;
#pragma unroll
        for (int n = 0; n < NST; ++n)
            h[n] = h[n] * expf(dtv * An[n]) + s * pr[DTRANK + n];
    }
    const float* pr = pb + (SEQ - 1) * 48;
    float yv = Dvec[d] * xv;
#pragma unroll
    for (int n = 0; n < NST; ++n) yv += h[n] * pr[DTRANK + NST + n];
    y[b * DI + d] = yv * silu_z[b * DI + d];
}

// flow[b, j] = sum_c y[b, c] * out_w[c, j]
__global__ void k_flow(const float* __restrict__ y, const float* __restrict__ out_w,
                       float* __restrict__ flow) {
    int b = blockIdx.x, j = threadIdx.x;
    const float* yr = y + b * DI;
    float acc = 0.f;
    for (int c = 0; c < DI; ++c) acc += yr[c] * out_w[c * DMODEL + j];
    flow[b * DMODEL + j] = acc;
}

// Decoder: one block per batch element, 512 threads (one per channel), loops 3 layers.
__global__ void __launch_bounds__(512) k_dec(
    const float* __restrict__ x, const float* __restrict__ flow,
    const float* __restrict__ in_w, const float* __restrict__ in_b,
    const float* __restrict__ flow_w, const float* __restrict__ dt_w,
    const float* __restrict__ dt_b, const float* __restrict__ A_log,
    const float* __restrict__ Dp, const float* __restrict__ out_w,
    const float* __restrict__ out_b, float* __restrict__ out) {
    __shared__ float flow_s[DMODEL];
    __shared__ float pf_s[48];
    __shared__ float bbox_s[4];
    __shared__ float red_s[8][4];
    int b = blockIdx.x, d = threadIdx.x;
    if (d < DMODEL) flow_s[d] = flow[b * DMODEL + d];
    if (d < 4) bbox_s[d] = x[(b * SEQ + SEQ - 1) * 8 + d];
    float h[NST];
#pragma unroll
    for (int n = 0; n < NST; ++n) h[n] = 0.f;
    __syncthreads();
    for (int L = 0; L < NLAYERS; ++L) {
        // bh = bbox @ in_w + in_b; split into e (silu) and r
        float epre = in_b[L * 2 * DID + d];
        float rpre = in_b[L * 2 * DID + DID + d];
#pragma unroll
        for (int i = 0; i < 4; ++i) {
            float bx = bbox_s[i];
            epre += bx * in_w[(L * 4 + i) * (2 * DID) + d];
            rpre += bx * in_w[(L * 4 + i) * (2 * DID) + DID + d];
        }
        float e = silu_f(epre);
        // pf = flow @ flow_w[L]  (48 outputs)
        if (d < 48) {
            float acc = 0.f;
            const float* fw = flow_w + L * DMODEL * 48;
            for (int c = 0; c < DMODEL; ++c) acc += flow_s[c] * fw[c * 48 + d];
            pf_s[d] = acc;
        }
        __syncthreads();
        float dtd = dt_b[L * DID + d];
#pragma unroll
        for (int r = 0; r < DTRANK; ++r) dtd += pf_s[r] * dt_w[(L * DTRANK + r) * DID + d];
        dtd = softplus_f(dtd);
        float yd = 0.f;
#pragma unroll
        for (int n = 0; n < NST; ++n) {
            float An = -expf(A_log[(L * DID + d) * NST + n]);
            h[n] = h[n] * expf(dtd * An) + e * (dtd * pf_s[DTRANK + n]);
            yd += h[n] * pf_s[DTRANK + NST + n];
        }
        yd += Dp[L * DID + d] * e;
        yd *= silu_f(rpre);
        // out = yd @ out_w[L] + out_b[L]  -> becomes next bbox
        int lane = d & 63, wid = d >> 6;
#pragma unroll
        for (int j = 0; j < 4; ++j) {
            float v = yd * out_w[(L * DID + d) * 4 + j];
#pragma unroll
            for (int off = 32; off; off >>= 1) v += __shfl_down(v, off, 64);
            if (lane == 0) red_s[wid][j] = v;
        }
        __syncthreads();
        if (d < 4) {
            float acc = out_b[L * 4 + d];
#pragma unroll
            for (int w = 0; w < 8; ++w) acc += red_s[w][d];
            bbox_s[d] = acc;
            if (L == NLAYERS - 1) out[b * 4 + d] = acc;
        }
        __syncthreads();
    }
}

extern "C" void kernel_launch(void* const* d_in, const int* in_sizes, int n_in,
                              void* d_out, int out_size, void* d_ws, size_t ws_size,
                              hipStream_t stream) {
    const float* x         = (const float*)d_in[0];
    const float* W_embed   = (const float*)d_in[1];
    const float* b_embed   = (const float*)d_in[2];
    const float* m_in_w    = (const float*)d_in[3];
    const float* m_conv_w  = (const float*)d_in[4];
    const float* m_conv_b  = (const float*)d_in[5];
    const float* m_xproj_w = (const float*)d_in[6];
    const float* m_dtproj_w= (const float*)d_in[7];
    const float* m_dtproj_b= (const float*)d_in[8];
    const float* m_A_log   = (const float*)d_in[9];
    const float* m_D       = (const float*)d_in[10];
    const float* m_out_w   = (const float*)d_in[11];
    const float* dec_in_w  = (const float*)d_in[12];
    const float* dec_in_b  = (const float*)d_in[13];
    const float* dec_flow_w= (const float*)d_in[14];
    const float* dec_dt_w  = (const float*)d_in[15];
    const float* dec_dt_b  = (const float*)d_in[16];
    const float* dec_A_log = (const float*)d_in[17];
    const float* dec_D     = (const float*)d_in[18];
    const float* dec_out_w = (const float*)d_in[19];
    const float* dec_out_b = (const float*)d_in[20];

    float* ws    = (float*)d_ws;
    float* W2    = ws;                       // 8*1024
    float* b2    = W2 + 8 * 1024;            // 1024
    float* xc    = b2 + 1024;                // 256*100*512 = 13107200
    float* proj  = xc + BATCH * SEQ * DI;    // 256*100*48  = 1228800
    float* siluz = proj + BATCH * SEQ * 48;  // 256*512
    float* yv    = siluz + BATCH * DI;       // 256*512
    float* flw   = yv + BATCH * DI;          // 256*256

    k_prep<<<4, 256, 0, stream>>>(W_embed, b_embed, m_in_w, W2, b2);
    k_conv<<<BATCH * SEQ * 2, 256, 0, stream>>>(x, W2, b2, m_conv_w, m_conv_b, xc, siluz);
    k_proj<<<BATCH * SEQ / 4, 192, 0, stream>>>(xc, m_xproj_w, proj);
    k_scan<<<BATCH * 2, 256, 0, stream>>>(xc, proj, m_A_log, m_dtproj_w, m_dtproj_b, m_D,
                                          siluz, yv);
    k_flow<<<BATCH, DMODEL, 0, stream>>>(yv, m_out_w, flw);
    k_dec<<<BATCH, DID, 0, stream>>>(x, flw, dec_in_w, dec_in_b, dec_flow_w, dec_dt_w,
                                     dec_dt_b, dec_A_log, dec_D, dec_out_w, dec_out_b,
                                     (float*)d_out);
}

// Round 2
// 321.301 us; speedup vs baseline: 1.3415x; 1.3415x over previous
//
#include <hip/hip_runtime.h>
#include <math.h>

#define BATCH 256
#define SEQ 100
#define DMODEL 256
#define DI 512
#define DID 512
#define NST 16
#define DTRANK 16
#define DCONV 4
#define NLAYERS 3

__device__ __forceinline__ float silu_f(float x) {
    return x / (1.0f + __expf(-x));
}
__device__ __forceinline__ float softplus_f(float x) {
    // log(1+exp(x)) = max(x,0) + log(1+exp(-|x|)); headroom vs threshold is ~2000x,
    // so the native log/exp (~5e-7 rel err) is safe.
    return fmaxf(x, 0.0f) + __logf(1.0f + __expf(-fabsf(x)));
}

// W2[i][j] = sum_c W_embed[i][c] * m_in_w[c][j];  b2[j] = sum_c b_embed[c] * m_in_w[c][j]
__global__ void k_prep(const float* __restrict__ W_embed, const float* __restrict__ b_embed,
                       const float* __restrict__ m_in_w, float* __restrict__ W2,
                       float* __restrict__ b2) {
    int j = blockIdx.x * blockDim.x + threadIdx.x;  // 0..1023
    float acc[8] = {0, 0, 0, 0, 0, 0, 0, 0};
    float accb = 0.f;
    for (int c = 0; c < DMODEL; ++c) {
        float w = m_in_w[c * 1024 + j];
        accb += b_embed[c] * w;
#pragma unroll
        for (int i = 0; i < 8; ++i) acc[i] += W_embed[i * DMODEL + c] * w;
    }
#pragma unroll
    for (int i = 0; i < 8; ++i) W2[i * 1024 + j] = acc[i];
    b2[j] = accb;
}

// xc[b,t,d] = silu( sum_k xs(b, t-3+k, d) * conv_w[d,k] + conv_b[d] )
// xs computed inline: xs(b,t',d) = sum_i x[b,t',i]*W2[i,d] + b2[d]   (0 if t'<0)
// At t==SEQ-1 also produce silu(z[b,d]) with z from W2 columns 512..1023.
__global__ void k_conv(const float* __restrict__ x, const float* __restrict__ W2,
                       const float* __restrict__ b2, const float* __restrict__ conv_w,
                       const float* __restrict__ conv_b, float* __restrict__ xc,
                       float* __restrict__ silu_z) {
    int bt = blockIdx.x >> 1;
    int d = ((blockIdx.x & 1) << 8) + threadIdx.x;  // 0..511
    int b = bt / SEQ, t = bt % SEQ;
    float w2c[8];
#pragma unroll
    for (int i = 0; i < 8; ++i) w2c[i] = W2[i * 1024 + d];
    float bias = b2[d];
    float xs[DCONV];
#pragma unroll
    for (int k = 0; k < DCONV; ++k) {
        int tp = t - (DCONV - 1) + k;
        float v = 0.f;
        if (tp >= 0) {
            const float* xr = x + (b * SEQ + tp) * 8;
            v = bias;
#pragma unroll
            for (int i = 0; i < 8; ++i) v += xr[i] * w2c[i];
        }
        xs[k] = v;
    }
    float acc = conv_b[d];
#pragma unroll
    for (int k = 0; k < DCONV; ++k) acc += xs[k] * conv_w[d * DCONV + k];
    xc[bt * DI + d] = silu_f(acc);
    if (t == SEQ - 1) {
        float z = b2[512 + d];
        const float* xr = x + (b * SEQ + t) * 8;
#pragma unroll
        for (int i = 0; i < 8; ++i) z += xr[i] * W2[i * 1024 + 512 + d];
        silu_z[b * DI + d] = silu_f(z);
    }
}

// proj[bt, j] = sum_c xc[bt, c] * xproj_w[c, j]   (j in 0..47)
__global__ void k_proj(const float* __restrict__ xc, const float* __restrict__ xproj_w,
                       float* __restrict__ proj) {
    int j = threadIdx.x % 48;
    int bt = blockIdx.x * 4 + threadIdx.x / 48;
    const float* row = xc + bt * DI;
    float acc = 0.f;
    for (int c = 0; c < DI; ++c) acc += row[c] * xproj_w[c * 48 + j];
    proj[bt * 48 + j] = acc;
}

// Sequential SSM scan over t; one thread per (b,d). Only final y (t=SEQ-1) kept.
__global__ void k_scan(const float* __restrict__ xc, const float* __restrict__ proj,
                       const float* __restrict__ A_log, const float* __restrict__ dtw,
                       const float* __restrict__ dtb, const float* __restrict__ Dvec,
                       const float* __restrict__ silu_z, float* __restrict__ y) {
    int b = blockIdx.x >> 1;
    int d = ((blockIdx.x & 1) << 8) + threadIdx.x;
    float An[NST], wr[DTRANK];
#pragma unroll
    for (int n = 0; n < NST; ++n) An[n] = -__expf(A_log[d * NST + n]);
#pragma unroll
    for (int r = 0; r < DTRANK; ++r) wr[r] = dtw[r * DI + d];
    float bdt = dtb[d];
    float h[NST];
#pragma unroll
    for (int n = 0; n < NST; ++n) h[n] = 0.f;
    float xv = 0.f;
    const float* pb = proj + (size_t)(b * SEQ) * 48;
    const float* xb = xc + (size_t)(b * SEQ) * DI;
    for (int t = 0; t < SEQ; ++t) {
        const float* pr = pb + t * 48;
        float acc = bdt;
#pragma unroll
        for (int r = 0; r < DTRANK; ++r) acc += pr[r] * wr[r];
        float dtv = softplus_f(acc);
        xv = xb[t * DI + d];
        float s = dtv * xv;
#pragma unroll
        for (int n = 0; n < NST; ++n)
            h[n] = h[n] * __expf(dtv * An[n]) + s * pr[DTRANK + n];
    }
    const float* pr = pb + (SEQ - 1) * 48;
    float yv = Dvec[d] * xv;
#pragma unroll
    for (int n = 0; n < NST; ++n) yv += h[n] * pr[DTRANK + NST + n];
    y[b * DI + d] = yv * silu_z[b * DI + d];
}

// flow[b, j] = sum_c y[b, c] * out_w[c, j]
__global__ void k_flow(const float* __restrict__ y, const float* __restrict__ out_w,
                       float* __restrict__ flow) {
    int b = blockIdx.x, j = threadIdx.x;
    const float* yr = y + b * DI;
    float acc = 0.f;
    for (int c = 0; c < DI; ++c) acc += yr[c] * out_w[c * DMODEL + j];
    flow[b * DMODEL + j] = acc;
}

// Decoder: one block per batch element, 512 threads (one per channel), loops 3 layers.
__global__ void __launch_bounds__(512) k_dec(
    const float* __restrict__ x, const float* __restrict__ flow,
    const float* __restrict__ in_w, const float* __restrict__ in_b,
    const float* __restrict__ flow_w, const float* __restrict__ dt_w,
    const float* __restrict__ dt_b, const float* __restrict__ A_log,
    const float* __restrict__ Dp, const float* __restrict__ out_w,
    const float* __restrict__ out_b, float* __restrict__ out) {
    __shared__ float flow_s[DMODEL];
    __shared__ float pf_s[48];
    __shared__ float bbox_s[4];
    __shared__ float red_s[8][4];
    int b = blockIdx.x, d = threadIdx.x;
    if (d < DMODEL) flow_s[d] = flow[b * DMODEL + d];
    if (d < 4) bbox_s[d] = x[(b * SEQ + SEQ - 1) * 8 + d];
    float h[NST];
#pragma unroll
    for (int n = 0; n < NST; ++n) h[n] = 0.f;
    __syncthreads();
    for (int L = 0; L < NLAYERS; ++L) {
        // bh = bbox @ in_w + in_b; split into e (silu) and r
        float epre = in_b[L * 2 * DID + d];
        float rpre = in_b[L * 2 * DID + DID + d];
#pragma unroll
        for (int i = 0; i < 4; ++i) {
            float bx = bbox_s[i];
            epre += bx * in_w[(L * 4 + i) * (2 * DID) + d];
            rpre += bx * in_w[(L * 4 + i) * (2 * DID) + DID + d];
        }
        float e = silu_f(epre);
        // pf = flow @ flow_w[L]  (48 outputs)
        if (d < 48) {
            float acc = 0.f;
            const float* fw = flow_w + L * DMODEL * 48;
            for (int c = 0; c < DMODEL; ++c) acc += flow_s[c] * fw[c * 48 + d];
            pf_s[d] = acc;
        }
        __syncthreads();
        float dtd = dt_b[L * DID + d];
#pragma unroll
        for (int r = 0; r < DTRANK; ++r) dtd += pf_s[r] * dt_w[(L * DTRANK + r) * DID + d];
        dtd = softplus_f(dtd);
        float yd = 0.f;
#pragma unroll
        for (int n = 0; n < NST; ++n) {
            float An = -__expf(A_log[(L * DID + d) * NST + n]);
            h[n] = h[n] * __expf(dtd * An) + e * (dtd * pf_s[DTRANK + n]);
            yd += h[n] * pf_s[DTRANK + NST + n];
        }
        yd += Dp[L * DID + d] * e;
        yd *= silu_f(rpre);
        // out = yd @ out_w[L] + out_b[L]  -> becomes next bbox
        int lane = d & 63, wid = d >> 6;
#pragma unroll
        for (int j = 0; j < 4; ++j) {
            float v = yd * out_w[(L * DID + d) * 4 + j];
#pragma unroll
            for (int off = 32; off; off >>= 1) v += __shfl_down(v, off, 64);
            if (lane == 0) red_s[wid][j] = v;
        }
        __syncthreads();
        if (d < 4) {
            float acc = out_b[L * 4 + d];
#pragma unroll
            for (int w = 0; w < 8; ++w) acc += red_s[w][d];
            bbox_s[d] = acc;
            if (L == NLAYERS - 1) out[b * 4 + d] = acc;
        }
        __syncthreads();
    }
}

extern "C" void kernel_launch(void* const* d_in, const int* in_sizes, int n_in,
                              void* d_out, int out_size, void* d_ws, size_t ws_size,
                              hipStream_t stream) {
    const float* x         = (const float*)d_in[0];
    const float* W_embed   = (const float*)d_in[1];
    const float* b_embed   = (const float*)d_in[2];
    const float* m_in_w    = (const float*)d_in[3];
    const float* m_conv_w  = (const float*)d_in[4];
    const float* m_conv_b  = (const float*)d_in[5];
    const float* m_xproj_w = (const float*)d_in[6];
    const float* m_dtproj_w= (const float*)d_in[7];
    const float* m_dtproj_b= (const float*)d_in[8];
    const float* m_A_log   = (const float*)d_in[9];
    const float* m_D       = (const float*)d_in[10];
    const float* m_out_w   = (const float*)d_in[11];
    const float* dec_in_w  = (const float*)d_in[12];
    const float* dec_in_b  = (const float*)d_in[13];
    const float* dec_flow_w= (const float*)d_in[14];
    const float* dec_dt_w  = (const float*)d_in[15];
    const float* dec_dt_b  = (const float*)d_in[16];
    const float* dec_A_log = (const float*)d_in[17];
    const float* dec_D     = (const float*)d_in[18];
    const float* dec_out_w = (const float*)d_in[19];
    const float* dec_out_b = (const float*)d_in[20];

    float* ws    = (float*)d_ws;
    float* W2    = ws;                       // 8*1024
    float* b2    = W2 + 8 * 1024;            // 1024
    float* xc    = b2 + 1024;                // 256*100*512 = 13107200
    float* proj  = xc + BATCH * SEQ * DI;    // 256*100*48  = 1228800
    float* siluz = proj + BATCH * SEQ * 48;  // 256*512
    float* yv    = siluz + BATCH * DI;       // 256*512
    float* flw   = yv + BATCH * DI;          // 256*256

    k_prep<<<4, 256, 0, stream>>>(W_embed, b_embed, m_in_w, W2, b2);
    k_conv<<<BATCH * SEQ * 2, 256, 0, stream>>>(x, W2, b2, m_conv_w, m_conv_b, xc, siluz);
    k_proj<<<BATCH * SEQ / 4, 192, 0, stream>>>(xc, m_xproj_w, proj);
    k_scan<<<BATCH * 2, 256, 0, stream>>>(xc, proj, m_A_log, m_dtproj_w, m_dtproj_b, m_D,
                                          siluz, yv);
    k_flow<<<BATCH, DMODEL, 0, stream>>>(yv, m_out_w, flw);
    k_dec<<<BATCH, DID, 0, stream>>>(x, flw, dec_in_w, dec_in_b, dec_flow_w, dec_dt_w,
                                     dec_dt_b, dec_A_log, dec_D, dec_out_w, dec_out_b,
                                     (float*)d_out);
}

// Round 3
// 203.833 us; speedup vs baseline: 2.1146x; 1.5763x over previous
//
#include <hip/hip_runtime.h>
#include <math.h>

#define BATCH 256
#define SEQ 100
#define DMODEL 256
#define DI 512
#define DID 512
#define NST 16
#define DTRANK 16
#define DCONV 4
#define NLAYERS 3

__device__ __forceinline__ float silu_f(float x) { return x / (1.0f + __expf(-x)); }
__device__ __forceinline__ float softplus_f(float x) {
    return fmaxf(x, 0.0f) + __logf(1.0f + __expf(-fabsf(x)));
}

// DPP butterfly add: VALU-pipe cross-lane reduce (no LDS-pipe ds_swizzle traffic).
#define DPP_ADD(v, ctrl, rmask) \
    v += __int_as_float(__builtin_amdgcn_update_dpp(0, __float_as_int(v), ctrl, rmask, 0xF, false))

// Full-wave (64) sum; result valid in lane 63 (other lanes partial).
__device__ __forceinline__ float wave64_sum(float v) {
    DPP_ADD(v, 0xB1, 0xF);   // quad_perm [1,0,3,2]  (xor 1)
    DPP_ADD(v, 0x4E, 0xF);   // quad_perm [2,3,0,1]  (xor 2)
    DPP_ADD(v, 0x141, 0xF);  // row_half_mirror      (xor within 8)
    DPP_ADD(v, 0x140, 0xF);  // row_mirror           (xor within 16)
    DPP_ADD(v, 0x142, 0xA);  // row_bcast15 -> rows 1,3
    DPP_ADD(v, 0x143, 0xC);  // row_bcast31 -> rows 2,3
    return v;
}

// W2[i][j] = sum_c W_embed[i][c] * m_in_w[c][j];  b2[j] = sum_c b_embed[c] * m_in_w[c][j]
__global__ void k_prep(const float* __restrict__ W_embed, const float* __restrict__ b_embed,
                       const float* __restrict__ m_in_w, float* __restrict__ W2,
                       float* __restrict__ b2) {
    int j = blockIdx.x * blockDim.x + threadIdx.x;  // 0..1023
    float acc[8] = {0, 0, 0, 0, 0, 0, 0, 0};
    float accb = 0.f;
    for (int c = 0; c < DMODEL; ++c) {
        float w = m_in_w[c * 1024 + j];
        accb += b_embed[c] * w;
#pragma unroll
        for (int i = 0; i < 8; ++i) acc[i] += W_embed[i * DMODEL + c] * w;
    }
#pragma unroll
    for (int i = 0; i < 8; ++i) W2[i * 1024 + j] = acc[i];
    b2[j] = accb;
}

// One block per batch element; thread d owns channel d end-to-end.
__global__ void __launch_bounds__(512, 2) k_fused(
    const float* __restrict__ x, const float* __restrict__ W2, const float* __restrict__ b2,
    const float* __restrict__ conv_w, const float* __restrict__ conv_b,
    const float* __restrict__ xproj_w, const float* __restrict__ dtw,
    const float* __restrict__ dtb, const float* __restrict__ A_log,
    const float* __restrict__ Dvec, const float* __restrict__ m_out_w,
    const float* __restrict__ dec_in_w, const float* __restrict__ dec_in_b,
    const float* __restrict__ dec_flow_w, const float* __restrict__ dec_dt_w,
    const float* __restrict__ dec_dt_b, const float* __restrict__ dec_A_log,
    const float* __restrict__ dec_D, const float* __restrict__ dec_out_w,
    const float* __restrict__ dec_out_b, float* __restrict__ out) {
    __shared__ float x_s[SEQ * 8];                   // this batch's raw input
    __shared__ float xs_s[DI];                       // conv output row (per t)
    __shared__ __align__(16) float pf_s[48];         // proj row (per t / per layer)
    __shared__ float y_s[DI];
    __shared__ float red_s[DMODEL];
    __shared__ float flow_s[DMODEL];
    __shared__ float bbox_s[4];
    __shared__ float dred_s[8][4];

    const int b = blockIdx.x;
    const int tid = threadIdx.x;
    const int d = tid;
    const int lane = tid & 63;
    const int wv = tid >> 6;  // wave 0..7; wave w owns proj cols 6w..6w+5

    for (int i = tid; i < SEQ * 8; i += 512) x_s[i] = x[b * SEQ * 8 + i];

    // ---- hoist per-channel weights into registers ----
    float w2c[8], w2z[8];
#pragma unroll
    for (int i = 0; i < 8; ++i) {
        w2c[i] = W2[i * 1024 + d];
        w2z[i] = W2[i * 1024 + 512 + d];
    }
    float biasc = b2[d], biasz = b2[512 + d];
    float cw[4];
    *(float4*)cw = *(const float4*)&conv_w[d * 4];
    float cb = conv_b[d];
    float xw[6][8];  // xproj weights for this wave's 6 cols, this lane's 8 c's
#pragma unroll
    for (int k = 0; k < 8; ++k) {
        int c = lane + 64 * k;
#pragma unroll
        for (int jj = 0; jj < 6; ++jj) xw[jj][k] = xproj_w[c * 48 + wv * 6 + jj];
    }
    float wr[DTRANK];
#pragma unroll
    for (int r = 0; r < DTRANK; ++r) wr[r] = dtw[r * DI + d];
    float bdt = dtb[d];
    float An[NST];  // -exp(A_log) * log2(e): use exp2f in the loop
#pragma unroll
    for (int n = 0; n < NST; ++n) An[n] = -__expf(A_log[d * NST + n]) * 1.44269504f;
    float h[NST];
#pragma unroll
    for (int n = 0; n < NST; ++n) h[n] = 0.f;

    float win0 = 0.f, win1 = 0.f, win2 = 0.f, win3 = 0.f;  // xs(t-3..t)
    float xcv = 0.f;
    __syncthreads();  // x_s ready

    // ---- encoder: conv + proj + dt + SSM scan, all per-t in one pass ----
#pragma unroll 4
    for (int t = 0; t < SEQ; ++t) {
        float4 xa = *(const float4*)&x_s[t * 8];
        float4 xb4 = *(const float4*)&x_s[t * 8 + 4];
        float xsv = biasc;
        xsv += xa.x * w2c[0] + xa.y * w2c[1] + xa.z * w2c[2] + xa.w * w2c[3];
        xsv += xb4.x * w2c[4] + xb4.y * w2c[5] + xb4.z * w2c[6] + xb4.w * w2c[7];
        win0 = win1; win1 = win2; win2 = win3; win3 = xsv;
        float cv = cb + win0 * cw[0] + win1 * cw[1] + win2 * cw[2] + win3 * cw[3];
        xcv = silu_f(cv);
        xs_s[d] = xcv;
        __syncthreads();
        // proj: wave wv computes cols 6wv..6wv+5 over all 512 c
        float xv8[8];
#pragma unroll
        for (int k = 0; k < 8; ++k) xv8[k] = xs_s[lane + 64 * k];
        float pj[6];
#pragma unroll
        for (int jj = 0; jj < 6; ++jj) {
            float a = 0.f;
#pragma unroll
            for (int k = 0; k < 8; ++k) a += xv8[k] * xw[jj][k];
            pj[jj] = wave64_sum(a);
        }
        if (lane == 63) {
#pragma unroll
            for (int jj = 0; jj < 6; ++jj) pf_s[wv * 6 + jj] = pj[jj];
        }
        __syncthreads();
        // dt = softplus(proj[:16] @ dtw + dtb)
        float4 p0 = *(const float4*)&pf_s[0];
        float4 p1 = *(const float4*)&pf_s[4];
        float4 p2 = *(const float4*)&pf_s[8];
        float4 p3 = *(const float4*)&pf_s[12];
        float acc = bdt;
        acc += p0.x * wr[0] + p0.y * wr[1] + p0.z * wr[2] + p0.w * wr[3];
        acc += p1.x * wr[4] + p1.y * wr[5] + p1.z * wr[6] + p1.w * wr[7];
        acc += p2.x * wr[8] + p2.y * wr[9] + p2.z * wr[10] + p2.w * wr[11];
        acc += p3.x * wr[12] + p3.y * wr[13] + p3.z * wr[14] + p3.w * wr[15];
        float dtv = softplus_f(acc);
        float s = dtv * xcv;
        float4 B0 = *(const float4*)&pf_s[16];
        float4 B1 = *(const float4*)&pf_s[20];
        float4 B2 = *(const float4*)&pf_s[24];
        float4 B3 = *(const float4*)&pf_s[28];
        float Bv[NST] = {B0.x, B0.y, B0.z, B0.w, B1.x, B1.y, B1.z, B1.w,
                         B2.x, B2.y, B2.z, B2.w, B3.x, B3.y, B3.z, B3.w};
#pragma unroll
        for (int n = 0; n < NST; ++n) h[n] = h[n] * exp2f(dtv * An[n]) + s * Bv[n];
    }
    // ---- final y, gate, write to LDS ----
    {
        float4 C0 = *(const float4*)&pf_s[32];
        float4 C1 = *(const float4*)&pf_s[36];
        float4 C2 = *(const float4*)&pf_s[40];
        float4 C3 = *(const float4*)&pf_s[44];
        float Cv[NST] = {C0.x, C0.y, C0.z, C0.w, C1.x, C1.y, C1.z, C1.w,
                         C2.x, C2.y, C2.z, C2.w, C3.x, C3.y, C3.z, C3.w};
        float yv = Dvec[d] * xcv;
#pragma unroll
        for (int n = 0; n < NST; ++n) yv += h[n] * Cv[n];
        float4 xe = *(const float4*)&x_s[(SEQ - 1) * 8];
        float4 xf = *(const float4*)&x_s[(SEQ - 1) * 8 + 4];
        float z = biasz;
        z += xe.x * w2z[0] + xe.y * w2z[1] + xe.z * w2z[2] + xe.w * w2z[3];
        z += xf.x * w2z[4] + xf.y * w2z[5] + xf.z * w2z[6] + xf.w * w2z[7];
        yv *= silu_f(z);
        y_s[d] = yv;
    }
    __syncthreads();
    // ---- flow = y @ m_out_w (256 outs; thread pair (j,p) splits the 512-sum) ----
    {
        int j = tid >> 1, p = tid & 1;
        float fa = 0.f;
#pragma unroll 4
        for (int i = 0; i < 64; ++i) {
            int c = p * 256 + 4 * i;
            float4 yq = *(const float4*)&y_s[c];
            fa += yq.x * m_out_w[(c + 0) * DMODEL + j];
            fa += yq.y * m_out_w[(c + 1) * DMODEL + j];
            fa += yq.z * m_out_w[(c + 2) * DMODEL + j];
            fa += yq.w * m_out_w[(c + 3) * DMODEL + j];
        }
        if (p == 1) red_s[j] = fa;
        __syncthreads();
        if (p == 0) flow_s[j] = fa + red_s[j];
        if (tid < 4) bbox_s[tid] = x_s[(SEQ - 1) * 8 + tid];
    }
#pragma unroll
    for (int n = 0; n < NST; ++n) h[n] = 0.f;  // decoder hidden state
    __syncthreads();
    // ---- decoder: 3 layers, per-b ----
    for (int L = 0; L < NLAYERS; ++L) {
        float epre = dec_in_b[L * 1024 + d];
        float rpre = dec_in_b[L * 1024 + 512 + d];
#pragma unroll
        for (int i = 0; i < 4; ++i) {
            float bx = bbox_s[i];
            epre += bx * dec_in_w[(L * 4 + i) * 1024 + d];
            rpre += bx * dec_in_w[(L * 4 + i) * 1024 + 512 + d];
        }
        float e = silu_f(epre);
        // pf = flow @ dec_flow_w[L]: wave wv -> cols 6wv..6wv+5 over 256 c
        float fl4[4];
#pragma unroll
        for (int k = 0; k < 4; ++k) fl4[k] = flow_s[lane + 64 * k];
        float pj[6];
#pragma unroll
        for (int jj = 0; jj < 6; ++jj) {
            float a = 0.f;
#pragma unroll
            for (int k = 0; k < 4; ++k)
                a += fl4[k] * dec_flow_w[L * DMODEL * 48 + (lane + 64 * k) * 48 + wv * 6 + jj];
            pj[jj] = wave64_sum(a);
        }
        if (lane == 63) {
#pragma unroll
            for (int jj = 0; jj < 6; ++jj) pf_s[wv * 6 + jj] = pj[jj];
        }
        __syncthreads();
        float4 p0 = *(const float4*)&pf_s[0];
        float4 p1 = *(const float4*)&pf_s[4];
        float4 p2 = *(const float4*)&pf_s[8];
        float4 p3 = *(const float4*)&pf_s[12];
        float dtd = dec_dt_b[L * DID + d];
        dtd += p0.x * dec_dt_w[(L * 16 + 0) * DID + d] + p0.y * dec_dt_w[(L * 16 + 1) * DID + d] +
               p0.z * dec_dt_w[(L * 16 + 2) * DID + d] + p0.w * dec_dt_w[(L * 16 + 3) * DID + d];
        dtd += p1.x * dec_dt_w[(L * 16 + 4) * DID + d] + p1.y * dec_dt_w[(L * 16 + 5) * DID + d] +
               p1.z * dec_dt_w[(L * 16 + 6) * DID + d] + p1.w * dec_dt_w[(L * 16 + 7) * DID + d];
        dtd += p2.x * dec_dt_w[(L * 16 + 8) * DID + d] + p2.y * dec_dt_w[(L * 16 + 9) * DID + d] +
               p2.z * dec_dt_w[(L * 16 + 10) * DID + d] + p2.w * dec_dt_w[(L * 16 + 11) * DID + d];
        dtd += p3.x * dec_dt_w[(L * 16 + 12) * DID + d] + p3.y * dec_dt_w[(L * 16 + 13) * DID + d] +
               p3.z * dec_dt_w[(L * 16 + 14) * DID + d] + p3.w * dec_dt_w[(L * 16 + 15) * DID + d];
        dtd = softplus_f(dtd);
        float4 B0 = *(const float4*)&pf_s[16];
        float4 B1 = *(const float4*)&pf_s[20];
        float4 B2 = *(const float4*)&pf_s[24];
        float4 B3 = *(const float4*)&pf_s[28];
        float4 C0 = *(const float4*)&pf_s[32];
        float4 C1 = *(const float4*)&pf_s[36];
        float4 C2 = *(const float4*)&pf_s[40];
        float4 C3 = *(const float4*)&pf_s[44];
        float Bv[NST] = {B0.x, B0.y, B0.z, B0.w, B1.x, B1.y, B1.z, B1.w,
                         B2.x, B2.y, B2.z, B2.w, B3.x, B3.y, B3.z, B3.w};
        float Cv[NST] = {C0.x, C0.y, C0.z, C0.w, C1.x, C1.y, C1.z, C1.w,
                         C2.x, C2.y, C2.z, C2.w, C3.x, C3.y, C3.z, C3.w};
        float yd = 0.f;
#pragma unroll
        for (int n = 0; n < NST; ++n) {
            float Adn = -__expf(dec_A_log[(L * DID + d) * NST + n]) * 1.44269504f;
            h[n] = h[n] * exp2f(dtd * Adn) + e * (dtd * Bv[n]);
            yd += h[n] * Cv[n];
        }
        yd += dec_D[L * DID + d] * e;
        yd *= silu_f(rpre);
        // out = yd @ dec_out_w[L] + b (4 outs): DPP wave sums + cross-wave LDS
#pragma unroll
        for (int jo = 0; jo < 4; ++jo) {
            float v = wave64_sum(yd * dec_out_w[(L * DID + d) * 4 + jo]);
            if (lane == 63) dred_s[wv][jo] = v;
        }
        __syncthreads();
        if (tid < 4) {
            float a2 = dec_out_b[L * 4 + tid];
#pragma unroll
            for (int w = 0; w < 8; ++w) a2 += dred_s[w][tid];
            bbox_s[tid] = a2;
            if (L == NLAYERS - 1) out[b * 4 + tid] = a2;
        }
        __syncthreads();
    }
}

extern "C" void kernel_launch(void* const* d_in, const int* in_sizes, int n_in,
                              void* d_out, int out_size, void* d_ws, size_t ws_size,
                              hipStream_t stream) {
    const float* x          = (const float*)d_in[0];
    const float* W_embed    = (const float*)d_in[1];
    const float* b_embed    = (const float*)d_in[2];
    const float* m_in_w     = (const float*)d_in[3];
    const float* m_conv_w   = (const float*)d_in[4];
    const float* m_conv_b   = (const float*)d_in[5];
    const float* m_xproj_w  = (const float*)d_in[6];
    const float* m_dtproj_w = (const float*)d_in[7];
    const float* m_dtproj_b = (const float*)d_in[8];
    const float* m_A_log    = (const float*)d_in[9];
    const float* m_D        = (const float*)d_in[10];
    const float* m_out_w    = (const float*)d_in[11];
    const float* dec_in_w   = (const float*)d_in[12];
    const float* dec_in_b   = (const float*)d_in[13];
    const float* dec_flow_w = (const float*)d_in[14];
    const float* dec_dt_w   = (const float*)d_in[15];
    const float* dec_dt_b   = (const float*)d_in[16];
    const float* dec_A_log  = (const float*)d_in[17];
    const float* dec_D      = (const float*)d_in[18];
    const float* dec_out_w  = (const float*)d_in[19];
    const float* dec_out_b  = (const float*)d_in[20];

    float* ws = (float*)d_ws;
    float* W2 = ws;            // 8*1024
    float* b2 = W2 + 8 * 1024; // 1024

    k_prep<<<4, 256, 0, stream>>>(W_embed, b_embed, m_in_w, W2, b2);
    k_fused<<<BATCH, 512, 0, stream>>>(x, W2, b2, m_conv_w, m_conv_b, m_xproj_w,
                                       m_dtproj_w, m_dtproj_b, m_A_log, m_D, m_out_w,
                                       dec_in_w, dec_in_b, dec_flow_w, dec_dt_w, dec_dt_b,
                                       dec_A_log, dec_D, dec_out_w, dec_out_b,
                                       (float*)d_out);
}

// Round 4
// 154.975 us; speedup vs baseline: 2.7813x; 1.3153x over previous
//
#include <hip/hip_runtime.h>
#include <math.h>

#define BATCH 256
#define SEQ 100
#define DMODEL 256
#define DI 512
#define DID 512
#define NST 16
#define DTRANK 16
#define DCONV 4
#define NLAYERS 3

// workspace layout (floats)
#define W2_OFF 0              // 8*1024
#define B2_OFF 8192           // 1024
#define WT_OFF 9216           // 48*512 transposed xproj
#define CWT_OFF 33792         // 4*512 transposed conv_w
#define FLAG_OFF 35840        // 2 ints (enc fast, dec fast)
#define PROJ_OFF 35848        // 25600*48
#define SILUZ_OFF 1264648     // 256*512
#define Y_OFF 1395720         // 256*512

__device__ __forceinline__ float silu_f(float x) { return x / (1.0f + __expf(-x)); }
__device__ __forceinline__ float softplus_f(float x) {
    return fmaxf(x, 0.0f) + __logf(1.0f + __expf(-fabsf(x)));
}

#define DPP_ADD(v, ctrl, rmask) \
    v += __int_as_float(__builtin_amdgcn_update_dpp(0, __float_as_int(v), ctrl, rmask, 0xF, false))

// Full-wave (64) sum; result valid in lane 63.
__device__ __forceinline__ float wave64_sum(float v) {
    DPP_ADD(v, 0xB1, 0xF);   // xor 1
    DPP_ADD(v, 0x4E, 0xF);   // xor 2
    DPP_ADD(v, 0x141, 0xF);  // row_half_mirror
    DPP_ADD(v, 0x140, 0xF);  // row_mirror
    DPP_ADD(v, 0x142, 0xA);  // row_bcast15
    DPP_ADD(v, 0x143, 0xC);  // row_bcast31
    return v;
}

// blocks 0-3: W2/b2 fold; 4-99: xproj transpose; 100-107: conv_w transpose;
// 108: A_log structure check (A[d][n] == (n+1)*A[d][0] within tol?)
__global__ void k_prep(const float* __restrict__ W_embed, const float* __restrict__ b_embed,
                       const float* __restrict__ m_in_w, const float* __restrict__ xproj_w,
                       const float* __restrict__ conv_w, const float* __restrict__ A_log,
                       const float* __restrict__ dec_A_log, float* __restrict__ ws,
                       int* __restrict__ flags) {
    int bid = blockIdx.x, tid = threadIdx.x;
    if (bid < 4) {
        int j = bid * 256 + tid;
        float acc[8] = {0, 0, 0, 0, 0, 0, 0, 0};
        float accb = 0.f;
        for (int c = 0; c < DMODEL; ++c) {
            float w = m_in_w[c * 1024 + j];
            accb += b_embed[c] * w;
#pragma unroll
            for (int i = 0; i < 8; ++i) acc[i] += W_embed[i * DMODEL + c] * w;
        }
#pragma unroll
        for (int i = 0; i < 8; ++i) ws[W2_OFF + i * 1024 + j] = acc[i];
        ws[B2_OFF + j] = accb;
    } else if (bid < 100) {
        int idx = (bid - 4) * 256 + tid;  // < 24576
        int j = idx / 512, c = idx % 512;
        ws[WT_OFF + j * 512 + c] = xproj_w[c * 48 + j];
    } else if (bid < 108) {
        int idx = (bid - 100) * 256 + tid;  // < 2048
        int tap = idx / 512, c = idx % 512;
        ws[CWT_OFF + tap * 512 + c] = conv_w[c * 4 + tap];
    } else {
        __shared__ int oks[2];
        if (tid == 0) { oks[0] = 1; oks[1] = 1; }
        __syncthreads();
        int bad_e = 0, bad_d = 0;
        for (int i = tid; i < DI * NST; i += 256) {
            int dd = i / NST, n = i % NST;
            float a0 = __expf(A_log[dd * NST]);
            float an = __expf(A_log[dd * NST + n]);
            if (fabsf(an - (n + 1) * a0) > 1e-4f * (n + 1)) bad_e = 1;
        }
        for (int i = tid; i < NLAYERS * DID * NST; i += 256) {
            int dd = i / NST, n = i % NST;
            float a0 = __expf(dec_A_log[dd * NST]);
            float an = __expf(dec_A_log[dd * NST + n]);
            if (fabsf(an - (n + 1) * a0) > 1e-4f * (n + 1)) bad_d = 1;
        }
        if (bad_e) atomicAnd(&oks[0], 0);
        if (bad_d) atomicAnd(&oks[1], 0);
        __syncthreads();
        if (tid == 0) { flags[0] = oks[0]; flags[1] = oks[1]; }
    }
}

// conv + proj, parallel over (b,t). Block = 4 waves; each wave 5 rows; block tile 20 t.
__global__ void __launch_bounds__(256, 3) k_convproj(
    const float* __restrict__ x, const float* __restrict__ ws, const float* __restrict__ conv_b,
    float* __restrict__ proj_g, float* __restrict__ silu_z) {
    __shared__ __align__(16) float xs_s[23 * 512];
    __shared__ __align__(16) float proj_s[20 * 48];
    const float* W2 = ws + W2_OFF;
    const float* b2 = ws + B2_OFF;
    const float* wT = ws + WT_OFF;
    const float* cwT = ws + CWT_OFF;
    const int b = blockIdx.x / 5, tb = blockIdx.x % 5, t0 = tb * 20;
    const int tid = threadIdx.x, lane = tid & 63, wv = tid >> 6;

    {  // phase1: xs rows t0-3..t0+19 -> LDS
        int c0 = tid, c1 = tid + 256;
        float wa[8], wb[8];
#pragma unroll
        for (int i = 0; i < 8; ++i) {
            wa[i] = W2[i * 1024 + c0];
            wb[i] = W2[i * 1024 + c1];
        }
        float ba = b2[c0], bbv = b2[c1];
        for (int r = 0; r < 23; ++r) {
            int t = t0 - 3 + r;
            float va = 0.f, vb = 0.f;
            if (t >= 0) {
                const float4* xr = (const float4*)(x + (size_t)(b * SEQ + t) * 8);
                float4 xlo = xr[0], xhi = xr[1];
                va = ba + xlo.x * wa[0] + xlo.y * wa[1] + xlo.z * wa[2] + xlo.w * wa[3] +
                     xhi.x * wa[4] + xhi.y * wa[5] + xhi.z * wa[6] + xhi.w * wa[7];
                vb = bbv + xlo.x * wb[0] + xlo.y * wb[1] + xlo.z * wb[2] + xlo.w * wb[3] +
                     xhi.x * wb[4] + xhi.y * wb[5] + xhi.z * wb[6] + xhi.w * wb[7];
            }
            xs_s[r * 512 + c0] = va;
            xs_s[r * 512 + c1] = vb;
        }
        if (tb == 4) {  // silu_z from last x row, W2 cols 512..1023
            const float4* xr = (const float4*)(x + (size_t)(b * SEQ + SEQ - 1) * 8);
            float4 xlo = xr[0], xhi = xr[1];
            float za = b2[512 + c0], zb = b2[512 + c1];
#pragma unroll
            for (int i = 0; i < 8; ++i) {
                float xi = (i < 4) ? ((const float*)&xlo)[i] : ((const float*)&xhi)[i - 4];
                za += xi * W2[i * 1024 + 512 + c0];
                zb += xi * W2[i * 1024 + 512 + c1];
            }
            silu_z[b * DI + c0] = silu_f(za);
            silu_z[b * DI + c1] = silu_f(zb);
        }
    }
    __syncthreads();
    {  // phase2: wave wv -> rows t0+wv*5 .. +4
        float cwr[8][4], cbr[8];
#pragma unroll
        for (int k = 0; k < 8; ++k) {
            int c = lane + 64 * k;
#pragma unroll
            for (int tap = 0; tap < 4; ++tap) cwr[k][tap] = cwT[tap * 512 + c];
            cbr[k] = conv_b[c];
        }
        float xcv[5][8];
#pragma unroll
        for (int q = 0; q < 5; ++q) {
            int rb = wv * 5 + q;  // xs_s row of t-3
#pragma unroll
            for (int k = 0; k < 8; ++k) {
                int c = lane + 64 * k;
                float a = cbr[k];
#pragma unroll
                for (int tap = 0; tap < 4; ++tap) a += cwr[k][tap] * xs_s[(rb + tap) * 512 + c];
                xcv[q][k] = silu_f(a);
            }
        }
        for (int j = 0; j < 48; ++j) {
            float wj[8];
#pragma unroll
            for (int k = 0; k < 8; ++k) wj[k] = wT[j * 512 + lane + 64 * k];
            float a0 = 0, a1 = 0, a2 = 0, a3 = 0, a4 = 0;
#pragma unroll
            for (int k = 0; k < 8; ++k) {
                float w = wj[k];
                a0 += xcv[0][k] * w;
                a1 += xcv[1][k] * w;
                a2 += xcv[2][k] * w;
                a3 += xcv[3][k] * w;
                a4 += xcv[4][k] * w;
            }
            a0 = wave64_sum(a0); a1 = wave64_sum(a1); a2 = wave64_sum(a2);
            a3 = wave64_sum(a3); a4 = wave64_sum(a4);
            if (lane == 63) {
                proj_s[(wv * 5 + 0) * 48 + j] = a0;
                proj_s[(wv * 5 + 1) * 48 + j] = a1;
                proj_s[(wv * 5 + 2) * 48 + j] = a2;
                proj_s[(wv * 5 + 3) * 48 + j] = a3;
                proj_s[(wv * 5 + 4) * 48 + j] = a4;
            }
        }
    }
    __syncthreads();
    if (tid < 240) {
        float4* dst = (float4*)(proj_g + (size_t)(b * SEQ + t0) * 48);
        dst[tid] = ((const float4*)proj_s)[tid];
    }
}

// SSM scan: thread per (b, d, t-half). h_full = h2 + exp(A*S2) .* h1.
__global__ void __launch_bounds__(512, 4) k_scan(
    const float* __restrict__ x, const float* __restrict__ ws, const float* __restrict__ conv_b,
    const float* __restrict__ proj_g, const float* __restrict__ A_log,
    const float* __restrict__ dtw, const float* __restrict__ dtb,
    const float* __restrict__ Dvec, const float* __restrict__ silu_z,
    const int* __restrict__ flags, float* __restrict__ y_g) {
    __shared__ __align__(16) float proj_l[SEQ * 48];
    __shared__ __align__(16) float x_l[SEQ * 8];
    __shared__ __align__(16) float h1_s[256 * 16];
    const int b = blockIdx.x >> 1, dgrp = blockIdx.x & 1;
    const int tid = threadIdx.x, half = tid >> 8, dl = tid & 255;
    const int d = dgrp * 256 + dl;
    const float* W2 = ws + W2_OFF;
    const float* b2 = ws + B2_OFF;
    const float* cwT = ws + CWT_OFF;

    for (int i = tid; i < SEQ * 48; i += 512) proj_l[i] = proj_g[(size_t)b * SEQ * 48 + i];
    for (int i = tid; i < SEQ * 8; i += 512) x_l[i] = x[(size_t)b * SEQ * 8 + i];

    float w2c[8];
#pragma unroll
    for (int i = 0; i < 8; ++i) w2c[i] = W2[i * 1024 + d];
    float biasc = b2[d];
    float cw0 = cwT[d], cw1 = cwT[512 + d], cw2 = cwT[1024 + d], cw3 = cwT[1536 + d];
    float cb = conv_b[d];
    float wr[DTRANK];
#pragma unroll
    for (int r = 0; r < DTRANK; ++r) wr[r] = dtw[r * DI + d];
    float bdt = dtb[d];
    float An0 = -__expf(A_log[d * NST]);  // == -1 for the given inputs
    const bool fast = flags[0] != 0;
    float h[NST];
#pragma unroll
    for (int n = 0; n < NST; ++n) h[n] = 0.f;
    float S = 0.f, xcv = 0.f;
    const int tstart = half * 50, tend = tstart + 50;
    __syncthreads();

    // conv window warmup: xs(tstart-3..tstart-1)
    float win0 = 0.f, win1 = 0.f, win2 = 0.f;
    for (int tt = tstart - 3; tt < tstart; ++tt) {
        float v = 0.f;
        if (tt >= 0) {
            const float4* xr = (const float4*)&x_l[tt * 8];
            float4 xa = xr[0], xb4 = xr[1];
            v = biasc + xa.x * w2c[0] + xa.y * w2c[1] + xa.z * w2c[2] + xa.w * w2c[3] +
                xb4.x * w2c[4] + xb4.y * w2c[5] + xb4.z * w2c[6] + xb4.w * w2c[7];
        }
        win0 = win1; win1 = win2; win2 = v;
    }

    for (int t = tstart; t < tend; ++t) {
        const float4* xr = (const float4*)&x_l[t * 8];
        float4 xa = xr[0], xb4 = xr[1];
        float xsv = biasc + xa.x * w2c[0] + xa.y * w2c[1] + xa.z * w2c[2] + xa.w * w2c[3] +
                    xb4.x * w2c[4] + xb4.y * w2c[5] + xb4.z * w2c[6] + xb4.w * w2c[7];
        float cv = cb + win0 * cw0 + win1 * cw1 + win2 * cw2 + xsv * cw3;
        win0 = win1; win1 = win2; win2 = xsv;
        xcv = silu_f(cv);
        const float* pr = &proj_l[t * 48];
        float4 p0 = *(const float4*)&pr[0];
        float4 p1 = *(const float4*)&pr[4];
        float4 p2 = *(const float4*)&pr[8];
        float4 p3 = *(const float4*)&pr[12];
        float acc = bdt;
        acc += p0.x * wr[0] + p0.y * wr[1] + p0.z * wr[2] + p0.w * wr[3];
        acc += p1.x * wr[4] + p1.y * wr[5] + p1.z * wr[6] + p1.w * wr[7];
        acc += p2.x * wr[8] + p2.y * wr[9] + p2.z * wr[10] + p2.w * wr[11];
        acc += p3.x * wr[12] + p3.y * wr[13] + p3.z * wr[14] + p3.w * wr[15];
        float dtv = softplus_f(acc);
        S += dtv;
        float s = dtv * xcv;
        float4 B0 = *(const float4*)&pr[16];
        float4 B1 = *(const float4*)&pr[20];
        float4 B2 = *(const float4*)&pr[24];
        float4 B3 = *(const float4*)&pr[28];
        float Bv[NST] = {B0.x, B0.y, B0.z, B0.w, B1.x, B1.y, B1.z, B1.w,
                         B2.x, B2.y, B2.z, B2.w, B3.x, B3.y, B3.z, B3.w};
        if (fast) {
            float E = __expf(dtv * An0);
            float Ek = 1.f;
#pragma unroll
            for (int n = 0; n < NST; ++n) {
                Ek *= E;
                h[n] = h[n] * Ek + s * Bv[n];
            }
        } else {
#pragma unroll
            for (int n = 0; n < NST; ++n) {
                float Ann = -__expf(A_log[d * NST + n]);
                h[n] = h[n] * __expf(dtv * Ann) + s * Bv[n];
            }
        }
    }
    if (half == 0) {
#pragma unroll
        for (int n = 0; n < NST; n += 4)
            *(float4*)&h1_s[dl * 16 + n] = make_float4(h[n], h[n + 1], h[n + 2], h[n + 3]);
    }
    __syncthreads();
    if (half == 1) {
        const float* pr = &proj_l[(SEQ - 1) * 48];
        float yv = Dvec[d] * xcv;
        if (fast) {
            float Gb = __expf(S * An0), Gk = 1.f;
#pragma unroll
            for (int n = 0; n < NST; ++n) {
                Gk *= Gb;
                float hf = h[n] + Gk * h1_s[dl * 16 + n];
                yv += hf * pr[32 + n];
            }
        } else {
#pragma unroll
            for (int n = 0; n < NST; ++n) {
                float Ann = -__expf(A_log[d * NST + n]);
                float hf = h[n] + __expf(S * Ann) * h1_s[dl * 16 + n];
                yv += hf * pr[32 + n];
            }
        }
        y_g[(size_t)b * DI + d] = yv * silu_z[(size_t)b * DI + d];
    }
}

// flow matvec + 3-layer decoder; one block per batch element.
__global__ void __launch_bounds__(512, 2) k_flowdec(
    const float* __restrict__ x, const float* __restrict__ y_g,
    const float* __restrict__ m_out_w, const float* __restrict__ dec_in_w,
    const float* __restrict__ dec_in_b, const float* __restrict__ dec_flow_w,
    const float* __restrict__ dec_dt_w, const float* __restrict__ dec_dt_b,
    const float* __restrict__ dec_A_log, const float* __restrict__ dec_D,
    const float* __restrict__ dec_out_w, const float* __restrict__ dec_out_b,
    const int* __restrict__ flags, float* __restrict__ out) {
    __shared__ __align__(16) float y_s[DI];
    __shared__ __align__(16) float pf_s[48];
    __shared__ float red_s[DMODEL];
    __shared__ float flow_s[DMODEL];
    __shared__ float bbox_s[4];
    __shared__ float dred_s[8][4];
    const int b = blockIdx.x, tid = threadIdx.x, d = tid;
    const int lane = tid & 63, wv = tid >> 6;
    const bool dfast = flags[1] != 0;
    y_s[d] = y_g[(size_t)b * DI + d];
    if (tid < 4) bbox_s[tid] = x[(size_t)(b * SEQ + SEQ - 1) * 8 + tid];
    __syncthreads();
    {
        int j = tid >> 1, p = tid & 1;
        float fa = 0.f;
#pragma unroll 4
        for (int i = 0; i < 64; ++i) {
            int c = p * 256 + 4 * i;
            float4 yq = *(const float4*)&y_s[c];
            fa += yq.x * m_out_w[(c + 0) * DMODEL + j];
            fa += yq.y * m_out_w[(c + 1) * DMODEL + j];
            fa += yq.z * m_out_w[(c + 2) * DMODEL + j];
            fa += yq.w * m_out_w[(c + 3) * DMODEL + j];
        }
        if (p == 1) red_s[j] = fa;
        __syncthreads();
        if (p == 0) flow_s[j] = fa + red_s[j];
    }
    float h[NST];
#pragma unroll
    for (int n = 0; n < NST; ++n) h[n] = 0.f;
    __syncthreads();
    for (int L = 0; L < NLAYERS; ++L) {
        float epre = dec_in_b[L * 1024 + d];
        float rpre = dec_in_b[L * 1024 + 512 + d];
#pragma unroll
        for (int i = 0; i < 4; ++i) {
            float bx = bbox_s[i];
            epre += bx * dec_in_w[(L * 4 + i) * 1024 + d];
            rpre += bx * dec_in_w[(L * 4 + i) * 1024 + 512 + d];
        }
        float e = silu_f(epre);
        float fl4[4];
#pragma unroll
        for (int k = 0; k < 4; ++k) fl4[k] = flow_s[lane + 64 * k];
        float pj[6];
#pragma unroll
        for (int jj = 0; jj < 6; ++jj) {
            float a = 0.f;
#pragma unroll
            for (int k = 0; k < 4; ++k)
                a += fl4[k] * dec_flow_w[L * DMODEL * 48 + (lane + 64 * k) * 48 + wv * 6 + jj];
            pj[jj] = wave64_sum(a);
        }
        if (lane == 63) {
#pragma unroll
            for (int jj = 0; jj < 6; ++jj) pf_s[wv * 6 + jj] = pj[jj];
        }
        __syncthreads();
        float4 p0 = *(const float4*)&pf_s[0];
        float4 p1 = *(const float4*)&pf_s[4];
        float4 p2 = *(const float4*)&pf_s[8];
        float4 p3 = *(const float4*)&pf_s[12];
        float dtd = dec_dt_b[L * DID + d];
        dtd += p0.x * dec_dt_w[(L * 16 + 0) * DID + d] + p0.y * dec_dt_w[(L * 16 + 1) * DID + d] +
               p0.z * dec_dt_w[(L * 16 + 2) * DID + d] + p0.w * dec_dt_w[(L * 16 + 3) * DID + d];
        dtd += p1.x * dec_dt_w[(L * 16 + 4) * DID + d] + p1.y * dec_dt_w[(L * 16 + 5) * DID + d] +
               p1.z * dec_dt_w[(L * 16 + 6) * DID + d] + p1.w * dec_dt_w[(L * 16 + 7) * DID + d];
        dtd += p2.x * dec_dt_w[(L * 16 + 8) * DID + d] + p2.y * dec_dt_w[(L * 16 + 9) * DID + d] +
               p2.z * dec_dt_w[(L * 16 + 10) * DID + d] + p2.w * dec_dt_w[(L * 16 + 11) * DID + d];
        dtd += p3.x * dec_dt_w[(L * 16 + 12) * DID + d] + p3.y * dec_dt_w[(L * 16 + 13) * DID + d] +
               p3.z * dec_dt_w[(L * 16 + 14) * DID + d] + p3.w * dec_dt_w[(L * 16 + 15) * DID + d];
        dtd = softplus_f(dtd);
        float4 B0 = *(const float4*)&pf_s[16];
        float4 B1 = *(const float4*)&pf_s[20];
        float4 B2 = *(const float4*)&pf_s[24];
        float4 B3 = *(const float4*)&pf_s[28];
        float4 C0 = *(const float4*)&pf_s[32];
        float4 C1 = *(const float4*)&pf_s[36];
        float4 C2 = *(const float4*)&pf_s[40];
        float4 C3 = *(const float4*)&pf_s[44];
        float Bv[NST] = {B0.x, B0.y, B0.z, B0.w, B1.x, B1.y, B1.z, B1.w,
                         B2.x, B2.y, B2.z, B2.w, B3.x, B3.y, B3.z, B3.w};
        float Cv[NST] = {C0.x, C0.y, C0.z, C0.w, C1.x, C1.y, C1.z, C1.w,
                         C2.x, C2.y, C2.z, C2.w, C3.x, C3.y, C3.z, C3.w};
        float yd = 0.f;
        if (dfast) {
            float Ad0 = -__expf(dec_A_log[(L * DID + d) * NST]);
            float E = __expf(dtd * Ad0), Ek = 1.f;
#pragma unroll
            for (int n = 0; n < NST; ++n) {
                Ek *= E;
                h[n] = h[n] * Ek + e * (dtd * Bv[n]);
                yd += h[n] * Cv[n];
            }
        } else {
#pragma unroll
            for (int n = 0; n < NST; ++n) {
                float Adn = -__expf(dec_A_log[(L * DID + d) * NST + n]);
                h[n] = h[n] * __expf(dtd * Adn) + e * (dtd * Bv[n]);
                yd += h[n] * Cv[n];
            }
        }
        yd += dec_D[L * DID + d] * e;
        yd *= silu_f(rpre);
#pragma unroll
        for (int jo = 0; jo < 4; ++jo) {
            float v = wave64_sum(yd * dec_out_w[(L * DID + d) * 4 + jo]);
            if (lane == 63) dred_s[wv][jo] = v;
        }
        __syncthreads();
        if (tid < 4) {
            float a2 = dec_out_b[L * 4 + tid];
#pragma unroll
            for (int w = 0; w < 8; ++w) a2 += dred_s[w][tid];
            bbox_s[tid] = a2;
            if (L == NLAYERS - 1) out[b * 4 + tid] = a2;
        }
        __syncthreads();
    }
}

extern "C" void kernel_launch(void* const* d_in, const int* in_sizes, int n_in,
                              void* d_out, int out_size, void* d_ws, size_t ws_size,
                              hipStream_t stream) {
    const float* x          = (const float*)d_in[0];
    const float* W_embed    = (const float*)d_in[1];
    const float* b_embed    = (const float*)d_in[2];
    const float* m_in_w     = (const float*)d_in[3];
    const float* m_conv_w   = (const float*)d_in[4];
    const float* m_conv_b   = (const float*)d_in[5];
    const float* m_xproj_w  = (const float*)d_in[6];
    const float* m_dtproj_w = (const float*)d_in[7];
    const float* m_dtproj_b = (const float*)d_in[8];
    const float* m_A_log    = (const float*)d_in[9];
    const float* m_D        = (const float*)d_in[10];
    const float* m_out_w    = (const float*)d_in[11];
    const float* dec_in_w   = (const float*)d_in[12];
    const float* dec_in_b   = (const float*)d_in[13];
    const float* dec_flow_w = (const float*)d_in[14];
    const float* dec_dt_w   = (const float*)d_in[15];
    const float* dec_dt_b   = (const float*)d_in[16];
    const float* dec_A_log  = (const float*)d_in[17];
    const float* dec_D      = (const float*)d_in[18];
    const float* dec_out_w  = (const float*)d_in[19];
    const float* dec_out_b  = (const float*)d_in[20];

    float* ws = (float*)d_ws;
    int* flags = (int*)(ws + FLAG_OFF);
    float* proj_g = ws + PROJ_OFF;
    float* siluz = ws + SILUZ_OFF;
    float* y_g = ws + Y_OFF;

    k_prep<<<109, 256, 0, stream>>>(W_embed, b_embed, m_in_w, m_xproj_w, m_conv_w,
                                    m_A_log, dec_A_log, ws, flags);
    k_convproj<<<BATCH * 5, 256, 0, stream>>>(x, ws, m_conv_b, proj_g, siluz);
    k_scan<<<BATCH * 2, 512, 0, stream>>>(x, ws, m_conv_b, proj_g, m_A_log, m_dtproj_w,
                                          m_dtproj_b, m_D, siluz, flags, y_g);
    k_flowdec<<<BATCH, 512, 0, stream>>>(x, y_g, m_out_w, dec_in_w, dec_in_b, dec_flow_w,
                                         dec_dt_w, dec_dt_b, dec_A_log, dec_D, dec_out_w,
                                         dec_out_b, flags, (float*)d_out);
}

// Round 6
// 148.459 us; speedup vs baseline: 2.9034x; 1.0439x over previous
//
#include <hip/hip_runtime.h>
#include <math.h>

#define BATCH 256
#define SEQ 100
#define DMODEL 256
#define DI 512
#define DID 512
#define NST 16
#define DTRANK 16
#define DCONV 4
#define NLAYERS 3

// workspace layout (floats)
#define W2_OFF 0              // 8*1024
#define B2_OFF 8192           // 1024
#define WT_OFF 9216           // 48*512 transposed xproj
#define CWT_OFF 33792         // 4*512 transposed conv_w
#define FLAG_OFF 35840        // 2 ints (enc fast, dec fast)
#define PROJ_OFF 35848        // 25600*48
#define SILUZ_OFF 1264648     // 256*512
#define Y_OFF 1395720         // 256*512

__device__ __forceinline__ float silu_f(float x) { return x / (1.0f + __expf(-x)); }

#define DPP_ADD(v, ctrl, rmask) \
    v += __int_as_float(__builtin_amdgcn_update_dpp(0, __float_as_int(v), ctrl, rmask, 0xF, false))

// Full-wave (64) sum; result valid in lane 63.
__device__ __forceinline__ float wave64_sum(float v) {
    DPP_ADD(v, 0xB1, 0xF);   // xor 1
    DPP_ADD(v, 0x4E, 0xF);   // xor 2
    DPP_ADD(v, 0x141, 0xF);  // row_half_mirror
    DPP_ADD(v, 0x140, 0xF);  // row_mirror
    DPP_ADD(v, 0x142, 0xA);  // row_bcast15
    DPP_ADD(v, 0x143, 0xC);  // row_bcast31
    return v;
}

// ---- scalar-load helpers: wave-uniform rows into SGPRs (prefetchable) ----
// base must be a block-uniform pointer (pure function of blockIdx/kernargs);
// the divergent-but-wave-uniform part goes through readfirstlane as a 32-bit
// byte offset in the SMEM register-soffset operand.
typedef float sf16 __attribute__((ext_vector_type(16)));
typedef float sf8 __attribute__((ext_vector_type(8)));

__device__ __forceinline__ int rfl(int v) { return __builtin_amdgcn_readfirstlane(v); }

#define SL2(dA, dB, base, offA, offB)                    \
    asm volatile("s_load_dwordx16 %0, %2, %3\n\t"        \
                 "s_load_dwordx16 %1, %2, %4"            \
                 : "=&s"(dA), "=&s"(dB)                  \
                 : "s"(base), "s"(offA), "s"(offB))
#define SLX(dX, base, off) \
    asm volatile("s_load_dwordx8 %0, %1, %2" : "=&s"(dX) : "s"(base), "s"(off))
#define SLC(dC, base, off) \
    asm volatile("s_load_dwordx16 %0, %1, %2" : "=&s"(dC) : "s"(base), "s"(off))
// Wait for in-flight s_loads; sched_barrier stops the compiler hoisting
// register-only consumers above the waitcnt (guide rule #18).
#define SL_WAIT()                                          \
    do {                                                   \
        asm volatile("s_waitcnt lgkmcnt(0)" ::: "memory"); \
        __builtin_amdgcn_sched_barrier(0);                 \
    } while (0)

// blocks 0-3: W2/b2 fold; 4-99: xproj transpose; 100-107: conv_w transpose;
// 108: A_log structure check (A[d][n] == (n+1)*A[d][0] within tol?)
__global__ void k_prep(const float* __restrict__ W_embed, const float* __restrict__ b_embed,
                       const float* __restrict__ m_in_w, const float* __restrict__ xproj_w,
                       const float* __restrict__ conv_w, const float* __restrict__ A_log,
                       const float* __restrict__ dec_A_log, float* __restrict__ ws,
                       int* __restrict__ flags) {
    int bid = blockIdx.x, tid = threadIdx.x;
    if (bid < 4) {
        int j = bid * 256 + tid;
        float acc[8] = {0, 0, 0, 0, 0, 0, 0, 0};
        float accb = 0.f;
        for (int c = 0; c < DMODEL; ++c) {
            float w = m_in_w[c * 1024 + j];
            accb += b_embed[c] * w;
#pragma unroll
            for (int i = 0; i < 8; ++i) acc[i] += W_embed[i * DMODEL + c] * w;
        }
#pragma unroll
        for (int i = 0; i < 8; ++i) ws[W2_OFF + i * 1024 + j] = acc[i];
        ws[B2_OFF + j] = accb;
    } else if (bid < 100) {
        int idx = (bid - 4) * 256 + tid;  // < 24576
        int j = idx / 512, c = idx % 512;
        ws[WT_OFF + j * 512 + c] = xproj_w[c * 48 + j];
    } else if (bid < 108) {
        int idx = (bid - 100) * 256 + tid;  // < 2048
        int tap = idx / 512, c = idx % 512;
        ws[CWT_OFF + tap * 512 + c] = conv_w[c * 4 + tap];
    } else {
        __shared__ int oks[2];
        if (tid == 0) { oks[0] = 1; oks[1] = 1; }
        __syncthreads();
        int bad_e = 0, bad_d = 0;
        for (int i = tid; i < DI * NST; i += 256) {
            int dd = i / NST, n = i % NST;
            float a0 = __expf(A_log[dd * NST]);
            float an = __expf(A_log[dd * NST + n]);
            if (fabsf(an - (n + 1) * a0) > 1e-4f * (n + 1)) bad_e = 1;
        }
        for (int i = tid; i < NLAYERS * DID * NST; i += 256) {
            int dd = i / NST, n = i % NST;
            float a0 = __expf(dec_A_log[dd * NST]);
            float an = __expf(dec_A_log[dd * NST + n]);
            if (fabsf(an - (n + 1) * a0) > 1e-4f * (n + 1)) bad_d = 1;
        }
        if (bad_e) atomicAnd(&oks[0], 0);
        if (bad_d) atomicAnd(&oks[1], 0);
        __syncthreads();
        if (tid == 0) { flags[0] = oks[0]; flags[1] = oks[1]; }
    }
}

// conv + proj, parallel over (b,t). Block = 4 waves; each wave 5 rows; block tile 20 t.
// Lane c-map: cA = 4*lane, cB = 256 + 4*lane -> all LDS/global traffic is
// stride-16B-per-lane b128 (conflict-free).
__global__ void __launch_bounds__(256, 3) k_convproj(
    const float* __restrict__ x, const float* __restrict__ ws, const float* __restrict__ conv_b,
    float* __restrict__ proj_g, float* __restrict__ silu_z) {
    __shared__ __align__(16) float xs_s[23 * 512];
    __shared__ __align__(16) float proj_s[20 * 48];
    const float* W2 = ws + W2_OFF;
    const float* b2 = ws + B2_OFF;
    const float* wT = ws + WT_OFF;
    const float* cwT = ws + CWT_OFF;
    const int b = blockIdx.x / 5, tb = blockIdx.x % 5, t0 = tb * 20;
    const int tid = threadIdx.x, lane = tid & 63, wv = tid >> 6;

    {  // phase1: thread owns channel pair (2tid, 2tid+1); rows t0-3..t0+19 -> LDS
        int c0 = tid * 2;
        float wa[8], wb[8];
#pragma unroll
        for (int i = 0; i < 8; ++i) {
            float2 wp = *(const float2*)&W2[i * 1024 + c0];
            wa[i] = wp.x;
            wb[i] = wp.y;
        }
        float2 bp = *(const float2*)&b2[c0];
        for (int r = 0; r < 23; ++r) {
            int t = t0 - 3 + r;
            float va = 0.f, vb = 0.f;
            if (t >= 0) {
                const float4* xr = (const float4*)(x + (size_t)(b * SEQ + t) * 8);
                float4 xlo = xr[0], xhi = xr[1];
                va = bp.x + xlo.x * wa[0] + xlo.y * wa[1] + xlo.z * wa[2] + xlo.w * wa[3] +
                     xhi.x * wa[4] + xhi.y * wa[5] + xhi.z * wa[6] + xhi.w * wa[7];
                vb = bp.y + xlo.x * wb[0] + xlo.y * wb[1] + xlo.z * wb[2] + xlo.w * wb[3] +
                     xhi.x * wb[4] + xhi.y * wb[5] + xhi.z * wb[6] + xhi.w * wb[7];
            }
            *(float2*)&xs_s[r * 512 + c0] = make_float2(va, vb);
        }
        if (tb == 4) {  // silu_z from last x row, W2 cols 512..1023
            const float4* xr = (const float4*)(x + (size_t)(b * SEQ + SEQ - 1) * 8);
            float4 xlo = xr[0], xhi = xr[1];
            float za = b2[512 + c0], zb = b2[512 + c0 + 1];
#pragma unroll
            for (int i = 0; i < 8; ++i) {
                float xi = (i < 4) ? ((const float*)&xlo)[i] : ((const float*)&xhi)[i - 4];
                float2 wp = *(const float2*)&W2[i * 1024 + 512 + c0];
                za += xi * wp.x;
                zb += xi * wp.y;
            }
            silu_z[b * DI + c0] = silu_f(za);
            silu_z[b * DI + c0 + 1] = silu_f(zb);
        }
    }
    __syncthreads();
    const int cA = lane * 4, cB = 256 + lane * 4;
    float xcv[5][8];
    {  // phase2a: conv+silu for this wave's 5 rows, 8 channels (4+4) per lane
        float4 cwA[4], cwB[4];
#pragma unroll
        for (int tap = 0; tap < 4; ++tap) {
            cwA[tap] = *(const float4*)&cwT[tap * 512 + cA];
            cwB[tap] = *(const float4*)&cwT[tap * 512 + cB];
        }
        float4 cbA = *(const float4*)&conv_b[cA];
        float4 cbB = *(const float4*)&conv_b[cB];
#pragma unroll
        for (int q = 0; q < 5; ++q) {
            int rb = wv * 5 + q;
            float4 aA = cbA, aB = cbB;
#pragma unroll
            for (int tap = 0; tap < 4; ++tap) {
                float4 xA = *(const float4*)&xs_s[(rb + tap) * 512 + cA];
                float4 xB = *(const float4*)&xs_s[(rb + tap) * 512 + cB];
                aA.x += cwA[tap].x * xA.x; aA.y += cwA[tap].y * xA.y;
                aA.z += cwA[tap].z * xA.z; aA.w += cwA[tap].w * xA.w;
                aB.x += cwB[tap].x * xB.x; aB.y += cwB[tap].y * xB.y;
                aB.z += cwB[tap].z * xB.z; aB.w += cwB[tap].w * xB.w;
            }
            xcv[q][0] = silu_f(aA.x); xcv[q][1] = silu_f(aA.y);
            xcv[q][2] = silu_f(aA.z); xcv[q][3] = silu_f(aA.w);
            xcv[q][4] = silu_f(aB.x); xcv[q][5] = silu_f(aB.y);
            xcv[q][6] = silu_f(aB.z); xcv[q][7] = silu_f(aB.w);
        }
    }
    {  // phase2b: proj over 48 cols; per j: 2 b128 loads + 40 FMA + DPP reduce
#pragma unroll 2
        for (int j = 0; j < 48; ++j) {
            float4 wA = *(const float4*)&wT[j * 512 + cA];
            float4 wB = *(const float4*)&wT[j * 512 + cB];
            float a0 = 0.f, a1 = 0.f, a2 = 0.f, a3 = 0.f, a4 = 0.f;
#pragma unroll
            for (int k = 0; k < 4; ++k) {
                float wk = ((const float*)&wA)[k];
                float wk2 = ((const float*)&wB)[k];
                a0 += xcv[0][k] * wk + xcv[0][4 + k] * wk2;
                a1 += xcv[1][k] * wk + xcv[1][4 + k] * wk2;
                a2 += xcv[2][k] * wk + xcv[2][4 + k] * wk2;
                a3 += xcv[3][k] * wk + xcv[3][4 + k] * wk2;
                a4 += xcv[4][k] * wk + xcv[4][4 + k] * wk2;
            }
            a0 = wave64_sum(a0); a1 = wave64_sum(a1); a2 = wave64_sum(a2);
            a3 = wave64_sum(a3); a4 = wave64_sum(a4);
            if (lane == 63) {
                proj_s[(wv * 5 + 0) * 48 + j] = a0;
                proj_s[(wv * 5 + 1) * 48 + j] = a1;
                proj_s[(wv * 5 + 2) * 48 + j] = a2;
                proj_s[(wv * 5 + 3) * 48 + j] = a3;
                proj_s[(wv * 5 + 4) * 48 + j] = a4;
            }
        }
    }
    __syncthreads();
    if (tid < 240) {
        float4* dst = (float4*)(proj_g + (size_t)(b * SEQ + t0) * 48);
        dst[tid] = ((const float4*)proj_s)[tid];
    }
}

// SSM scan: t split in 2 halves per (b,d); proj/x rows fetched via prefetched
// s_loads (wave-uniform -> SGPRs, no LDS in the t-loop).
#define SCAN_STEP(SA, SB, SX)                                                        \
    do {                                                                             \
        float xsv = biasc;                                                           \
        xsv = fmaf((SX)[0], w2c[0], xsv); xsv = fmaf((SX)[1], w2c[1], xsv);          \
        xsv = fmaf((SX)[2], w2c[2], xsv); xsv = fmaf((SX)[3], w2c[3], xsv);          \
        xsv = fmaf((SX)[4], w2c[4], xsv); xsv = fmaf((SX)[5], w2c[5], xsv);          \
        xsv = fmaf((SX)[6], w2c[6], xsv); xsv = fmaf((SX)[7], w2c[7], xsv);          \
        float cv = cb + win0 * cw0 + win1 * cw1 + win2 * cw2 + xsv * cw3;            \
        win0 = win1; win1 = win2; win2 = xsv;                                        \
        xcv = silu_f(cv);                                                            \
        float acc = bdt;                                                             \
        acc = fmaf((SA)[0], wr[0], acc);  acc = fmaf((SA)[1], wr[1], acc);           \
        acc = fmaf((SA)[2], wr[2], acc);  acc = fmaf((SA)[3], wr[3], acc);           \
        acc = fmaf((SA)[4], wr[4], acc);  acc = fmaf((SA)[5], wr[5], acc);           \
        acc = fmaf((SA)[6], wr[6], acc);  acc = fmaf((SA)[7], wr[7], acc);           \
        acc = fmaf((SA)[8], wr[8], acc);  acc = fmaf((SA)[9], wr[9], acc);           \
        acc = fmaf((SA)[10], wr[10], acc); acc = fmaf((SA)[11], wr[11], acc);        \
        acc = fmaf((SA)[12], wr[12], acc); acc = fmaf((SA)[13], wr[13], acc);        \
        acc = fmaf((SA)[14], wr[14], acc); acc = fmaf((SA)[15], wr[15], acc);        \
        float dtv = (acc > 20.f) ? acc : __logf(1.f + __expf(acc));                  \
        S += dtv;                                                                    \
        float sv = dtv * xcv;                                                        \
        if (fast) {                                                                  \
            float E1 = __expf(dtv * An0);                                            \
            float E2 = E1 * E1, E3 = E2 * E1, E4 = E2 * E2;                          \
            float E5 = E4 * E1, E6 = E4 * E2, E7 = E4 * E3, E8 = E4 * E4;            \
            float E9 = E8 * E1, E10 = E8 * E2, E11 = E8 * E3, E12 = E8 * E4;         \
            float E13 = E8 * E5, E14 = E8 * E6, E15 = E8 * E7, E16 = E8 * E8;        \
            h[0] = fmaf(h[0], E1, sv * (SB)[0]);   h[1] = fmaf(h[1], E2, sv * (SB)[1]); \
            h[2] = fmaf(h[2], E3, sv * (SB)[2]);   h[3] = fmaf(h[3], E4, sv * (SB)[3]); \
            h[4] = fmaf(h[4], E5, sv * (SB)[4]);   h[5] = fmaf(h[5], E6, sv * (SB)[5]); \
            h[6] = fmaf(h[6], E7, sv * (SB)[6]);   h[7] = fmaf(h[7], E8, sv * (SB)[7]); \
            h[8] = fmaf(h[8], E9, sv * (SB)[8]);   h[9] = fmaf(h[9], E10, sv * (SB)[9]); \
            h[10] = fmaf(h[10], E11, sv * (SB)[10]); h[11] = fmaf(h[11], E12, sv * (SB)[11]); \
            h[12] = fmaf(h[12], E13, sv * (SB)[12]); h[13] = fmaf(h[13], E14, sv * (SB)[13]); \
            h[14] = fmaf(h[14], E15, sv * (SB)[14]); h[15] = fmaf(h[15], E16, sv * (SB)[15]); \
        } else {                                                                     \
            _Pragma("unroll")                                                        \
            for (int n = 0; n < NST; ++n) {                                          \
                float Ann = -__expf(A_log[d * NST + n]);                             \
                h[n] = fmaf(h[n], __expf(dtv * Ann), sv * (SB)[n]);                  \
            }                                                                        \
        }                                                                            \
    } while (0)

__global__ void __launch_bounds__(512, 4) k_scan(
    const float* __restrict__ x, const float* __restrict__ ws, const float* __restrict__ conv_b,
    const float* __restrict__ proj_g, const float* __restrict__ A_log,
    const float* __restrict__ dtw, const float* __restrict__ dtb,
    const float* __restrict__ Dvec, const float* __restrict__ silu_z,
    const int* __restrict__ flags, float* __restrict__ y_g) {
    __shared__ float h1_s[256 * 17];  // stride 17: conflict-free
    const int b = blockIdx.x >> 1, dgrp = blockIdx.x & 1;
    const int tid = threadIdx.x, half = tid >> 8, dl = tid & 255;
    const int d = dgrp * 256 + dl;
    const float* W2 = ws + W2_OFF;
    const float* b2 = ws + B2_OFF;
    const float* cwT = ws + CWT_OFF;
    const float* proj_b = proj_g + (size_t)b * SEQ * 48;  // block-uniform
    const float* x_b = x + (size_t)b * SEQ * 8;           // block-uniform

    float w2c[8];
#pragma unroll
    for (int i = 0; i < 8; ++i) w2c[i] = W2[i * 1024 + d];
    float biasc = b2[d];
    float cw0 = cwT[d], cw1 = cwT[512 + d], cw2 = cwT[1024 + d], cw3 = cwT[1536 + d];
    float cb = conv_b[d];
    float wr[DTRANK];
#pragma unroll
    for (int r = 0; r < DTRANK; ++r) wr[r] = dtw[r * DI + d];
    float bdt = dtb[d];
    float An0 = -__expf(A_log[d * NST]);
    const bool fast = flags[0] != 0;
    float h[NST];
#pragma unroll
    for (int n = 0; n < NST; ++n) h[n] = 0.f;
    float S = 0.f, xcv = 0.f;
    const int tstart = half * 50;

    // conv window warmup: xs(tstart-3..tstart-1)
    float win0 = 0.f, win1 = 0.f, win2 = 0.f;
    for (int tt = tstart - 3; tt < tstart; ++tt) {
        float v = 0.f;
        if (tt >= 0) {
            const float4* xr = (const float4*)(x_b + tt * 8);
            float4 xa = xr[0], xb4 = xr[1];
            v = biasc + xa.x * w2c[0] + xa.y * w2c[1] + xa.z * w2c[2] + xa.w * w2c[3] +
                xb4.x * w2c[4] + xb4.y * w2c[5] + xb4.z * w2c[6] + xb4.w * w2c[7];
        }
        win0 = win1; win1 = win2; win2 = v;
    }

    // wave-uniform byte offsets (readfirstlane -> SGPR)
    int poff = rfl(tstart * 192);  // proj row stride 48*4 B
    int xoff = rfl(tstart * 32);   // x row stride 8*4 B
    sf16 a0, a1, b0, b1;
    sf8 ax, bx;
    SL2(a0, a1, proj_b, poff, poff + 64);
    SLX(ax, x_b, xoff);
    SL_WAIT();
    for (int it = 0; it < 25; ++it) {
        int p1 = poff + 192, x1 = xoff + 32;
        SL2(b0, b1, proj_b, p1, p1 + 64);
        SLX(bx, x_b, x1);
        SCAN_STEP(a0, a1, ax);
        SL_WAIT();
        // prefetch t+2 (last iteration: re-read t+1's row; result unused)
        int p2 = (it < 24) ? poff + 384 : p1;
        int x2 = (it < 24) ? xoff + 64 : x1;
        SL2(a0, a1, proj_b, p2, p2 + 64);
        SLX(ax, x_b, x2);
        SCAN_STEP(b0, b1, bx);
        SL_WAIT();
        poff += 384;
        xoff += 64;
    }

    if (half == 0) {
#pragma unroll
        for (int n = 0; n < NST; ++n) h1_s[dl * 17 + n] = h[n];
    }
    __syncthreads();
    if (half == 1) {
        sf16 cC;
        SLC(cC, proj_b, (SEQ - 1) * 192 + 128);  // C row: floats 32..47 of t=99
        SL_WAIT();
        float yv = Dvec[d] * xcv;
        if (fast) {
            float G1 = __expf(S * An0);
            float G2 = G1 * G1, G3 = G2 * G1, G4 = G2 * G2;
            float G5 = G4 * G1, G6 = G4 * G2, G7 = G4 * G3, G8 = G4 * G4;
            float G9 = G8 * G1, G10 = G8 * G2, G11 = G8 * G3, G12 = G8 * G4;
            float G13 = G8 * G5, G14 = G8 * G6, G15 = G8 * G7, G16 = G8 * G8;
            float Gs[NST] = {G1, G2, G3, G4, G5, G6, G7, G8,
                             G9, G10, G11, G12, G13, G14, G15, G16};
#pragma unroll
            for (int n = 0; n < NST; ++n) {
                float hf = fmaf(h1_s[dl * 17 + n], Gs[n], h[n]);
                yv = fmaf(hf, cC[n], yv);
            }
        } else {
#pragma unroll
            for (int n = 0; n < NST; ++n) {
                float Ann = -__expf(A_log[d * NST + n]);
                float hf = fmaf(h1_s[dl * 17 + n], __expf(S * Ann), h[n]);
                yv = fmaf(hf, cC[n], yv);
            }
        }
        y_g[(size_t)b * DI + d] = yv * silu_z[(size_t)b * DI + d];
    }
}

// flow matvec + 3-layer decoder; one block per batch element.
__global__ void __launch_bounds__(512, 2) k_flowdec(
    const float* __restrict__ x, const float* __restrict__ y_g,
    const float* __restrict__ m_out_w, const float* __restrict__ dec_in_w,
    const float* __restrict__ dec_in_b, const float* __restrict__ dec_flow_w,
    const float* __restrict__ dec_dt_w, const float* __restrict__ dec_dt_b,
    const float* __restrict__ dec_A_log, const float* __restrict__ dec_D,
    const float* __restrict__ dec_out_w, const float* __restrict__ dec_out_b,
    const int* __restrict__ flags, float* __restrict__ out) {
    __shared__ __align__(16) float y_s[DI];
    __shared__ __align__(16) float pf_s[48];
    __shared__ float red_s[DMODEL];
    __shared__ float flow_s[DMODEL];
    __shared__ float bbox_s[4];
    __shared__ float dred_s[8][4];
    const int b = blockIdx.x, tid = threadIdx.x, d = tid;
    const int lane = tid & 63, wv = tid >> 6;
    const bool dfast = flags[1] != 0;
    y_s[d] = y_g[(size_t)b * DI + d];
    if (tid < 4) bbox_s[tid] = x[(size_t)(b * SEQ + SEQ - 1) * 8 + tid];
    __syncthreads();
    {
        int j = tid >> 1, p = tid & 1;
        float fa = 0.f;
#pragma unroll 4
        for (int i = 0; i < 64; ++i) {
            int c = p * 256 + 4 * i;
            float4 yq = *(const float4*)&y_s[c];
            fa += yq.x * m_out_w[(c + 0) * DMODEL + j];
            fa += yq.y * m_out_w[(c + 1) * DMODEL + j];
            fa += yq.z * m_out_w[(c + 2) * DMODEL + j];
            fa += yq.w * m_out_w[(c + 3) * DMODEL + j];
        }
        if (p == 1) red_s[j] = fa;
        __syncthreads();
        if (p == 0) flow_s[j] = fa + red_s[j];
    }
    float h[NST];
#pragma unroll
    for (int n = 0; n < NST; ++n) h[n] = 0.f;
    __syncthreads();
    for (int L = 0; L < NLAYERS; ++L) {
        float epre = dec_in_b[L * 1024 + d];
        float rpre = dec_in_b[L * 1024 + 512 + d];
#pragma unroll
        for (int i = 0; i < 4; ++i) {
            float bx = bbox_s[i];
            epre += bx * dec_in_w[(L * 4 + i) * 1024 + d];
            rpre += bx * dec_in_w[(L * 4 + i) * 1024 + 512 + d];
        }
        float e = silu_f(epre);
        float fl4[4];
#pragma unroll
        for (int k = 0; k < 4; ++k) fl4[k] = flow_s[lane + 64 * k];
        float pj[6];
#pragma unroll
        for (int jj = 0; jj < 6; ++jj) {
            float a = 0.f;
#pragma unroll
            for (int k = 0; k < 4; ++k)
                a += fl4[k] * dec_flow_w[L * DMODEL * 48 + (lane + 64 * k) * 48 + wv * 6 + jj];
            pj[jj] = wave64_sum(a);
        }
        if (lane == 63) {
#pragma unroll
            for (int jj = 0; jj < 6; ++jj) pf_s[wv * 6 + jj] = pj[jj];
        }
        __syncthreads();
        float4 p0 = *(const float4*)&pf_s[0];
        float4 p1 = *(const float4*)&pf_s[4];
        float4 p2 = *(const float4*)&pf_s[8];
        float4 p3 = *(const float4*)&pf_s[12];
        float dtd = dec_dt_b[L * DID + d];
        dtd += p0.x * dec_dt_w[(L * 16 + 0) * DID + d] + p0.y * dec_dt_w[(L * 16 + 1) * DID + d] +
               p0.z * dec_dt_w[(L * 16 + 2) * DID + d] + p0.w * dec_dt_w[(L * 16 + 3) * DID + d];
        dtd += p1.x * dec_dt_w[(L * 16 + 4) * DID + d] + p1.y * dec_dt_w[(L * 16 + 5) * DID + d] +
               p1.z * dec_dt_w[(L * 16 + 6) * DID + d] + p1.w * dec_dt_w[(L * 16 + 7) * DID + d];
        dtd += p2.x * dec_dt_w[(L * 16 + 8) * DID + d] + p2.y * dec_dt_w[(L * 16 + 9) * DID + d] +
               p2.z * dec_dt_w[(L * 16 + 10) * DID + d] + p2.w * dec_dt_w[(L * 16 + 11) * DID + d];
        dtd += p3.x * dec_dt_w[(L * 16 + 12) * DID + d] + p3.y * dec_dt_w[(L * 16 + 13) * DID + d] +
               p3.z * dec_dt_w[(L * 16 + 14) * DID + d] + p3.w * dec_dt_w[(L * 16 + 15) * DID + d];
        dtd = (dtd > 20.f) ? dtd : __logf(1.f + __expf(dtd));
        float4 B0 = *(const float4*)&pf_s[16];
        float4 B1 = *(const float4*)&pf_s[20];
        float4 B2 = *(const float4*)&pf_s[24];
        float4 B3 = *(const float4*)&pf_s[28];
        float4 C0 = *(const float4*)&pf_s[32];
        float4 C1 = *(const float4*)&pf_s[36];
        float4 C2 = *(const float4*)&pf_s[40];
        float4 C3 = *(const float4*)&pf_s[44];
        float Bv[NST] = {B0.x, B0.y, B0.z, B0.w, B1.x, B1.y, B1.z, B1.w,
                         B2.x, B2.y, B2.z, B2.w, B3.x, B3.y, B3.z, B3.w};
        float Cv[NST] = {C0.x, C0.y, C0.z, C0.w, C1.x, C1.y, C1.z, C1.w,
                         C2.x, C2.y, C2.z, C2.w, C3.x, C3.y, C3.z, C3.w};
        float yd = 0.f;
        if (dfast) {
            float Ad0 = -__expf(dec_A_log[(L * DID + d) * NST]);
            float E1 = __expf(dtd * Ad0);
            float E2 = E1 * E1, E3 = E2 * E1, E4 = E2 * E2;
            float E5 = E4 * E1, E6 = E4 * E2, E7 = E4 * E3, E8 = E4 * E4;
            float E9 = E8 * E1, E10 = E8 * E2, E11 = E8 * E3, E12 = E8 * E4;
            float E13 = E8 * E5, E14 = E8 * E6, E15 = E8 * E7, E16 = E8 * E8;
            float Es[NST] = {E1, E2, E3, E4, E5, E6, E7, E8,
                             E9, E10, E11, E12, E13, E14, E15, E16};
#pragma unroll
            for (int n = 0; n < NST; ++n) {
                h[n] = fmaf(h[n], Es[n], e * (dtd * Bv[n]));
                yd += h[n] * Cv[n];
            }
        } else {
#pragma unroll
            for (int n = 0; n < NST; ++n) {
                float Adn = -__expf(dec_A_log[(L * DID + d) * NST + n]);
                h[n] = fmaf(h[n], __expf(dtd * Adn), e * (dtd * Bv[n]));
                yd += h[n] * Cv[n];
            }
        }
        yd += dec_D[L * DID + d] * e;
        yd *= silu_f(rpre);
#pragma unroll
        for (int jo = 0; jo < 4; ++jo) {
            float v = wave64_sum(yd * dec_out_w[(L * DID + d) * 4 + jo]);
            if (lane == 63) dred_s[wv][jo] = v;
        }
        __syncthreads();
        if (tid < 4) {
            float a2 = dec_out_b[L * 4 + tid];
#pragma unroll
            for (int w = 0; w < 8; ++w) a2 += dred_s[w][tid];
            bbox_s[tid] = a2;
            if (L == NLAYERS - 1) out[b * 4 + tid] = a2;
        }
        __syncthreads();
    }
}

extern "C" void kernel_launch(void* const* d_in, const int* in_sizes, int n_in,
                              void* d_out, int out_size, void* d_ws, size_t ws_size,
                              hipStream_t stream) {
    const float* x          = (const float*)d_in[0];
    const float* W_embed    = (const float*)d_in[1];
    const float* b_embed    = (const float*)d_in[2];
    const float* m_in_w     = (const float*)d_in[3];
    const float* m_conv_w   = (const float*)d_in[4];
    const float* m_conv_b   = (const float*)d_in[5];
    const float* m_xproj_w  = (const float*)d_in[6];
    const float* m_dtproj_w = (const float*)d_in[7];
    const float* m_dtproj_b = (const float*)d_in[8];
    const float* m_A_log    = (const float*)d_in[9];
    const float* m_D        = (const float*)d_in[10];
    const float* m_out_w    = (const float*)d_in[11];
    const float* dec_in_w   = (const float*)d_in[12];
    const float* dec_in_b   = (const float*)d_in[13];
    const float* dec_flow_w = (const float*)d_in[14];
    const float* dec_dt_w   = (const float*)d_in[15];
    const float* dec_dt_b   = (const float*)d_in[16];
    const float* dec_A_log  = (const float*)d_in[17];
    const float* dec_D      = (const float*)d_in[18];
    const float* dec_out_w  = (const float*)d_in[19];
    const float* dec_out_b  = (const float*)d_in[20];

    float* ws = (float*)d_ws;
    int* flags = (int*)(ws + FLAG_OFF);
    float* proj_g = ws + PROJ_OFF;
    float* siluz = ws + SILUZ_OFF;
    float* y_g = ws + Y_OFF;

    k_prep<<<109, 256, 0, stream>>>(W_embed, b_embed, m_in_w, m_xproj_w, m_conv_w,
                                    m_A_log, dec_A_log, ws, flags);
    k_convproj<<<BATCH * 5, 256, 0, stream>>>(x, ws, m_conv_b, proj_g, siluz);
    k_scan<<<BATCH * 2, 512, 0, stream>>>(x, ws, m_conv_b, proj_g, m_A_log, m_dtproj_w,
                                          m_dtproj_b, m_D, siluz, flags, y_g);
    k_flowdec<<<BATCH, 512, 0, stream>>>(x, y_g, m_out_w, dec_in_w, dec_in_b, dec_flow_w,
                                         dec_dt_w, dec_dt_b, dec_A_log, dec_D, dec_out_w,
                                         dec_out_b, flags, (float*)d_out);
}